// Round 17
// baseline (330.272 us; speedup 1.0000x reference)
//
#include <hip/hip_runtime.h>

typedef unsigned short u16;
typedef unsigned int u32;
typedef __attribute__((ext_vector_type(4))) float f32x4;
typedef __attribute__((ext_vector_type(8))) short bf16x8;   // 8 bf16 bit-patterns (4 VGPRs)
typedef __attribute__((ext_vector_type(8))) u16 u16x8;
typedef __attribute__((ext_vector_type(4))) u16 u16x4;
typedef __attribute__((ext_vector_type(4))) u32 u32x4;

#define GLOB_AS __attribute__((address_space(1)))
#define LDS_AS  __attribute__((address_space(3)))

__device__ __forceinline__ void gload_lds16(const void* g, void* l) {
  // async global->LDS, 16B per lane, LDS dest = wave-uniform base + lane*16
  __builtin_amdgcn_global_load_lds((const GLOB_AS void*)g, (LDS_AS void*)l, 16, 0, 0);
}

__device__ __forceinline__ u16 f2bf(float f) {  // RNE float->bf16
  u32 u = __builtin_bit_cast(u32, f);
  u += 0x7fffu + ((u >> 16) & 1u);
  return (u16)(u >> 16);
}

__device__ __forceinline__ float bf2f(u16 b) {
  u32 u = (u32)b << 16;
  return __builtin_bit_cast(float, u);
}

#define MFMA16(a, b, c) __builtin_amdgcn_mfma_f32_16x16x32_bf16(a, b, c, 0, 0, 0)

// ---------------- fused cast f32 -> bf16 for x + 4 weight matrices ----------------
__global__ __launch_bounds__(256) void cast_all(const float* __restrict__ x,
                                                const float* __restrict__ wq,
                                                const float* __restrict__ wk,
                                                const float* __restrict__ wv,
                                                const float* __restrict__ wo,
                                                u16* __restrict__ xb, u16* __restrict__ wqb,
                                                u16* __restrict__ wkb, u16* __restrict__ wvb,
                                                u16* __restrict__ wob) {
  int i = blockIdx.x * 256 + threadIdx.x;  // 8-element units; boundaries block-uniform
  const float* s;
  u16* d;
  int off;
  if (i < 819200)       { s = x;  d = xb;  off = i; }
  else if (i < 1343488) { s = wq; d = wqb; off = i - 819200; }
  else if (i < 1867776) { s = wk; d = wkb; off = i - 1343488; }
  else if (i < 2392064) { s = wv; d = wvb; off = i - 1867776; }
  else                  { s = wo; d = wob; off = i - 2392064; }
  f32x4 a = ((const f32x4*)s)[2 * off], b = ((const f32x4*)s)[2 * off + 1];
  u16x8 o;
  o[0] = f2bf(a[0]); o[1] = f2bf(a[1]); o[2] = f2bf(a[2]); o[3] = f2bf(a[3]);
  o[4] = f2bf(b[0]); o[5] = f2bf(b[1]); o[6] = f2bf(b[2]); o[7] = f2bf(b[3]);
  ((u16x8*)d)[off] = o;
}

// GEMM K-loop pipeline: dbuf LDS (wide-row XOR layout), prefetch 2 deep, counted
// vmcnt(8), 1 barrier pair per K-step.  (round-14 verified)
#define GEMM_BODY(C_WRITE)                                                        \
  f32x4 acc[4][4] = {};                                                           \
  const u32 dstoff = wave * 2048 + lane * 8; /* u16 units; +512 per chunk */      \
  int gsb = 0;                                                                    \
  const u16* Agp = Ag;                                                            \
  const u16* Bgp = Bg;                                                            \
  _Pragma("unroll") for (int pf = 0; pf < 2; ++pf) {                              \
    u16* ad = &As[gsb][0] + dstoff;                                               \
    u16* bd = &Bs[gsb][0] + dstoff;                                               \
    gload_lds16(Agp, ad);                                                         \
    gload_lds16(Agp + (size_t)8 * K + d4, ad + 512);                              \
    gload_lds16(Agp + (size_t)16 * K, ad + 1024);                                 \
    gload_lds16(Agp + (size_t)24 * K + d4, ad + 1536);                            \
    gload_lds16(Bgp, bd);                                                         \
    gload_lds16(Bgp + (size_t)8 * K + d4, bd + 512);                              \
    gload_lds16(Bgp + (size_t)16 * K, bd + 1024);                                 \
    gload_lds16(Bgp + (size_t)24 * K + d4, bd + 1536);                            \
    Agp += 64;                                                                    \
    Bgp += 64;                                                                    \
    gsb ^= 1;                                                                     \
  }                                                                               \
  for (int it = 0; it < 32; ++it) {                                               \
    const int buf = it & 1;                                                       \
    if (it < 31)                                                                  \
      asm volatile("s_waitcnt vmcnt(8)" ::: "memory");                            \
    else                                                                          \
      asm volatile("s_waitcnt vmcnt(0)" ::: "memory");                            \
    __builtin_amdgcn_s_barrier();                                                 \
    _Pragma("unroll") for (int kk = 0; kk < 64; kk += 32) {                       \
      bf16x8 af[4], bfr[4];                                                       \
      _Pragma("unroll") for (int mi = 0; mi < 4; mi++)                            \
          af[mi] = *(const bf16x8*)&As[buf][((wr + mi * 16 + li) >> 1) * 128 +    \
              ((((kk >> 3) + lg + 8 * (li & 1)) ^ (li >> 1)) * 8)];               \
      _Pragma("unroll") for (int ni = 0; ni < 4; ni++)                            \
          bfr[ni] = *(const bf16x8*)&Bs[buf][((wc + ni * 16 + li) >> 1) * 128 +   \
              ((((kk >> 3) + lg + 8 * (li & 1)) ^ (li >> 1)) * 8)];               \
      _Pragma("unroll") for (int mi = 0; mi < 4; mi++)                            \
          _Pragma("unroll") for (int ni = 0; ni < 4; ni++)                        \
              acc[mi][ni] = MFMA16(af[mi], bfr[ni], acc[mi][ni]);                 \
    }                                                                             \
    __builtin_amdgcn_s_barrier();                                                 \
    if (it <= 29) {                                                               \
      u16* ad = &As[gsb][0] + dstoff;                                             \
      u16* bd = &Bs[gsb][0] + dstoff;                                             \
      gload_lds16(Agp, ad);                                                       \
      gload_lds16(Agp + (size_t)8 * K + d4, ad + 512);                            \
      gload_lds16(Agp + (size_t)16 * K, ad + 1024);                               \
      gload_lds16(Agp + (size_t)24 * K + d4, ad + 1536);                          \
      gload_lds16(Bgp, bd);                                                       \
      gload_lds16(Bgp + (size_t)8 * K + d4, bd + 512);                            \
      gload_lds16(Bgp + (size_t)16 * K, bd + 1024);                               \
      gload_lds16(Bgp + (size_t)24 * K + d4, bd + 1536);                          \
      Agp += 64;                                                                  \
      Bgp += 64;                                                                  \
      gsb ^= 1;                                                                   \
    }                                                                             \
  }                                                                               \
  float bcol[4];                                                                  \
  _Pragma("unroll") for (int ni = 0; ni < 4; ni++)                                \
      bcol[ni] = bias[n0 + wc + ni * 16 + li];                                    \
  _Pragma("unroll") for (int mi = 0; mi < 4; mi++) {                              \
    _Pragma("unroll") for (int ni = 0; ni < 4; ni++) {                            \
      const int gm = m0 + wr + mi * 16 + lg * 4;                                  \
      const int gn = n0 + wc + ni * 16 + li;                                      \
      _Pragma("unroll") for (int r = 0; r < 4; r++) { C_WRITE; }                  \
    }                                                                             \
  }

#define GEMM_STAGE_SETUP()                                        \
  const int Wl = lane >> 4;                                       \
  const int sl = lane & 15;                                       \
  const int gsa = sl ^ Wl;                                        \
  const int d4 = ((((gsa & 7) ^ 4) - (gsa & 7)) * 8)

// ---------------- fused QKV NT GEMM, XCD-chunked; bf16 outputs; pipelined ----------------
__global__ __launch_bounds__(256) void gemm_qkv(const u16* __restrict__ A,
                                                const u16* __restrict__ Bq,
                                                const u16* __restrict__ Bk,
                                                const u16* __restrict__ Bv,
                                                const float* __restrict__ bq,
                                                const float* __restrict__ bk,
                                                const float* __restrict__ bv,
                                                u16* __restrict__ Cq,
                                                u16* __restrict__ Ck,
                                                u16* __restrict__ Cv) {
  constexpr int K = 2048, N = 2048;
  __shared__ u16 As[2][128 * 64];
  __shared__ u16 Bs[2][128 * 64];
  const int tid = threadIdx.x;
  const int wave = tid >> 6, lane = tid & 63;
  const int lg = lane >> 4, li = lane & 15;
  const int lid = blockIdx.x + 25 * blockIdx.y;   // 0..1199, xcd ~ lid&7
  const int tile = (lid & 7) * 150 + (lid >> 3);  // bijective (1200 = 8*150)
  const int bx = tile % 25, by = tile / 25;
  const int m0 = bx * 128;
  const int mat = by >> 4;  // block-uniform
  const int n0 = (by & 15) * 128;
  const u16* B = (mat == 0) ? Bq : (mat == 1) ? Bk : Bv;
  const float* bias = (mat == 0) ? bq : (mat == 1) ? bk : bv;
  u16* C = (mat == 0) ? Cq : (mat == 1) ? Ck : Cv;
  const int wr = (wave >> 1) * 64, wc = (wave & 1) * 64;

  GEMM_STAGE_SETUP();
  const u16* Ag = A + (size_t)(m0 + wave * 32 + 2 * Wl + (sl >> 3)) * K + (gsa & 7) * 8;
  const u16* Bg = B + (size_t)(n0 + wave * 32 + 2 * Wl + (sl >> 3)) * K + (gsa & 7) * 8;

  GEMM_BODY(C[(size_t)(gm + r) * N + gn] = f2bf(acc[mi][ni][r] + bcol[ni]))
}

// ---------------- NT GEMM (out-proj), XCD-chunked, f32 out; pipelined ----------------
__global__ __launch_bounds__(256) void gemm_nt(const u16* __restrict__ A,
                                               const u16* __restrict__ B,
                                               const float* __restrict__ bias,
                                               float* __restrict__ C) {
  constexpr int K = 2048, N = 2048;
  __shared__ u16 As[2][128 * 64];
  __shared__ u16 Bs[2][128 * 64];
  const int tid = threadIdx.x;
  const int wave = tid >> 6, lane = tid & 63;
  const int lg = lane >> 4, li = lane & 15;
  const int lid = blockIdx.x + 25 * blockIdx.y;  // 0..399
  const int tile = (lid & 7) * 50 + (lid >> 3);  // bijective (400 = 8*50)
  const int m0 = (tile % 25) * 128, n0 = (tile / 25) * 128;
  const int wr = (wave >> 1) * 64, wc = (wave & 1) * 64;

  GEMM_STAGE_SETUP();
  const u16* Ag = A + (size_t)(m0 + wave * 32 + 2 * Wl + (sl >> 3)) * K + (gsa & 7) * 8;
  const u16* Bg = B + (size_t)(n0 + wave * 32 + 2 * Wl + (sl >> 3)) * K + (gsa & 7) * 8;

  GEMM_BODY(C[(size_t)(gm + r) * N + gn] = acc[mi][ni][r] + bcol[ni])
}

// ---------------- fused RMSNorm + 3-axis RoPE, bf16 in, q and k in one dispatch ----------------
__global__ __launch_bounds__(256) void rms_rope2(const u16* __restrict__ preq,
                                                 const u16* __restrict__ prek,
                                                 const float* __restrict__ wq,
                                                 const float* __restrict__ wk,
                                                 const float* __restrict__ fcos,
                                                 const float* __restrict__ fsin,
                                                 u16* __restrict__ outq,
                                                 u16* __restrict__ outk, float foldq) {
  const int isk = blockIdx.x >= 3200;  // block-uniform
  const int l = isk ? blockIdx.x - 3200 : blockIdx.x;
  const u16* pre = isk ? prek : preq;
  const float* w = isk ? wk : wq;
  u16* out = isk ? outk : outq;
  const float fold = isk ? 1.0f : foldq;
  const int tid = threadIdx.x;
  const int d0 = tid * 8;
  u16x8 pv = *(const u16x8*)(pre + (size_t)l * 2048 + d0);
  float xv[8];
#pragma unroll
  for (int j = 0; j < 8; j++) xv[j] = bf2f(pv[j]);
  float ss = (xv[0] * xv[0] + xv[1] * xv[1]) + (xv[2] * xv[2] + xv[3] * xv[3]) +
             (xv[4] * xv[4] + xv[5] * xv[5]) + (xv[6] * xv[6] + xv[7] * xv[7]);
#pragma unroll
  for (int m = 32; m; m >>= 1) ss += __shfl_xor(ss, m);
  __shared__ float red[4];
  if ((tid & 63) == 0) red[tid >> 6] = ss;
  __syncthreads();
  const float scale =
      rsqrtf((red[0] + red[1] + red[2] + red[3]) * (1.0f / 2048.0f) + 1e-6f) * fold;
  f32x4 w0 = *(const f32x4*)(w + d0);
  f32x4 w1 = *(const f32x4*)(w + d0 + 4);
  float xs[8];
#pragma unroll
  for (int j = 0; j < 4; j++) {
    xs[j] = xv[j] * w0[j] * scale;
    xs[4 + j] = xv[4 + j] * w1[j] * scale;
  }
  const int f = l / 640, rem = l % 640;
  const int hh = rem >> 5, ww = rem & 31;
  const int cb = (d0 & 127) >> 1;
  u16x8 ov;
#pragma unroll
  for (int i = 0; i < 4; i++) {
    const int c = cb + i;
    const int prow = c < 22 ? f : (c < 43 ? hh : ww);  // S0=22, S0+S1=43
    const float fc = fcos[prow * 64 + c];
    const float fs = fsin[prow * 64 + c];
    const float xr = xs[2 * i], xi = xs[2 * i + 1];
    ov[2 * i] = f2bf(xr * fc - xi * fs);
    ov[2 * i + 1] = f2bf(xr * fs + xi * fc);
  }
  *(u16x8*)(out + (size_t)l * 2048 + d0) = ov;
}

// ---------------- bf16 transpose [3200][2048] -> [2048][3200], pi-permuted ----------------
// Also zeroes the attn work-queue counter (block 0) for the following dispatch.
__global__ __launch_bounds__(256) void transpose_2d(const u16* __restrict__ src,
                                                    u16* __restrict__ dst,
                                                    int* __restrict__ counter) {
  if (blockIdx.x == 0 && blockIdx.y == 0 && threadIdx.x == 0) *counter = 0;
  __shared__ u16 t[64][72];
  const int m0 = blockIdx.x * 64, n0 = blockIdx.y * 64;
  const int tid = threadIdx.x;
  const int r = tid >> 3, c8 = (tid & 7) * 8;
#pragma unroll
  for (int j = 0; j < 2; j++) {
    u16x8 v = *(const u16x8*)&src[(size_t)(m0 + r + 32 * j) * 2048 + n0 + c8];
#pragma unroll
    for (int e = 0; e < 8; e++) t[c8 + e][r + 32 * j] = v[e];
  }
  __syncthreads();
  const int b = (c8 >> 5) * 32;       // 32-block base within tile
  const int cc = ((c8 >> 3) & 3) * 4; // 4-col group
#pragma unroll
  for (int j = 0; j < 2; j++) {
    const u16* trow = &t[r + 32 * j][0];
    u16x4 lo = *(const u16x4*)&trow[b + cc];
    u16x4 hi = *(const u16x4*)&trow[b + 16 + cc];
    u16x8 v;
    v[0] = lo[0]; v[1] = lo[1]; v[2] = lo[2]; v[3] = lo[3];
    v[4] = hi[0]; v[5] = hi[1]; v[6] = hi[2]; v[7] = hi[3];
    *(u16x8*)&dst[(size_t)(n0 + r + 32 * j) * 3200 + m0 + c8] = v;
  }
}

// ---------------- flash attention v9: persistent blocks + dynamic work queue ----------------
// 512 blocks x 8 waves (2/CU, all resident). 800 items = 25 qtile128 x 16 heads x 2 KV-halves,
// pulled via device-scope atomic. Fixed-shift softmax (P = exp2(s-24)) -> split needs only
// per-row l for recombination. Inner loop = round-16 verified body (25-iter constants).
__global__ __launch_bounds__(512) void attn_kernel(const u16* __restrict__ Q,
                                                   const u16* __restrict__ Kb,
                                                   const u16* __restrict__ VT,
                                                   u16* __restrict__ Opart,
                                                   float* __restrict__ ml,
                                                   int* __restrict__ counter) {
  __shared__ u16 Klds[2][64 * 128];
  __shared__ u16 Vlds[2][128 * 64];
  __shared__ int curit;
  const int tid = threadIdx.x, wave = tid >> 6, lane = tid & 63;
  const int lg = lane >> 4, li = lane & 15;

  // item-independent staging lane constants
  const int klp = lane >> 4;                 // 0..3
  const int kg0 = (lane & 15) ^ klp;         // granule for j=0 (row&7 = klp)
  const int kd4 = ((kg0 ^ 4) - kg0) * 8;     // j=1: granule ^= 4
  const int vlp = lane >> 3;                 // 0..7
  const int vg = (lane & 7) ^ vlp;           // granule (row&7 = vlp)
  const u32 dstoff = wave * 1024 + lane * 8; // u16 units; +512 per gload j

  for (;;) {
    if (tid == 0) curit = atomicAdd(counter, 1);
    __syncthreads();  // broadcast item + protect LDS from previous item's readers
    const int item = curit;
    if (item >= 800) return;
    const int split = item & 1;
    const int h = (item >> 1) & 15;
    const int qt = item >> 5;  // 0..24
    const int qrow0 = qt * 128 + wave * 16;
    const int n0 = split * 1600;

    bf16x8 qf[4];
    {
      const u16* qb = Q + (size_t)(qrow0 + li) * 2048 + h * 128 + lg * 8;
#pragma unroll
      for (int ks = 0; ks < 4; ks++) qf[ks] = *(const bf16x8*)(qb + ks * 32);
    }
    f32x4 o[8] = {};
    float lrow = 0.f;

    const u16* kp = Kb + (size_t)(n0 + wave * 8 + klp) * 2048 + h * 128 + kg0 * 8;
    const u16* vp = VT + (size_t)(h * 128 + wave * 16 + vlp) * 3200 + n0 + vg * 8;
    int sb = 0;

#define STAGE()                               \
  do {                                        \
    u16* kd = &Klds[sb][0] + dstoff;          \
    u16* vd = &Vlds[sb][0] + dstoff;          \
    gload_lds16(kp, kd);                      \
    gload_lds16(kp + 4 * 2048 + kd4, kd + 512); \
    gload_lds16(vp, vd);                      \
    gload_lds16(vp + 8 * 3200, vd + 512);     \
    kp += 64 * 2048;                          \
    vp += 64;                                 \
    sb ^= 1;                                  \
  } while (0)

    STAGE();  // iter 0
    STAGE();  // iter 1

    for (int it = 0; it < 25; ++it) {
      const int buf = it & 1;
      if (it < 24)
        asm volatile("s_waitcnt vmcnt(4)" ::: "memory");  // this iter's 4 landed
      else
        asm volatile("s_waitcnt vmcnt(0)" ::: "memory");
      __builtin_amdgcn_s_barrier();

      // QK^T swapped: s4[t][i] = S[kv=16t+4lg+i][q=li]
      f32x4 s4[4] = {};
#pragma unroll
      for (int t = 0; t < 4; t++)
#pragma unroll
        for (int ks = 0; ks < 4; ks++) {
          const bf16x8 kf = *(const bf16x8*)&Klds[buf][(t * 16 + li) * 128 +
                                                       ((ks * 4 + lg) ^ (li & 7)) * 8];
          s4[t] = MFMA16(kf, qf[ks], s4[t]);
        }
      // fixed-shift softmax: P = exp2(s - 24), no max tracking
      f32x4 p[4];
#pragma unroll
      for (int t = 0; t < 4; t++)
#pragma unroll
        for (int i = 0; i < 4; i++) p[t][i] = exp2f(s4[t][i] - 24.0f);
      lrow += ((p[0][0] + p[0][1]) + (p[0][2] + p[0][3])) +
              ((p[1][0] + p[1][1]) + (p[1][2] + p[1][3])) +
              ((p[2][0] + p[2][1]) + (p[2][2] + p[2][3])) +
              ((p[3][0] + p[3][1]) + (p[3][2] + p[3][3]));
      u32 wp[8];
      asm("v_cvt_pk_bf16_f32 %0, %1, %2" : "=v"(wp[0]) : "v"(p[0][0]), "v"(p[0][1]));
      asm("v_cvt_pk_bf16_f32 %0, %1, %2" : "=v"(wp[1]) : "v"(p[0][2]), "v"(p[0][3]));
      asm("v_cvt_pk_bf16_f32 %0, %1, %2" : "=v"(wp[2]) : "v"(p[1][0]), "v"(p[1][1]));
      asm("v_cvt_pk_bf16_f32 %0, %1, %2" : "=v"(wp[3]) : "v"(p[1][2]), "v"(p[1][3]));
      asm("v_cvt_pk_bf16_f32 %0, %1, %2" : "=v"(wp[4]) : "v"(p[2][0]), "v"(p[2][1]));
      asm("v_cvt_pk_bf16_f32 %0, %1, %2" : "=v"(wp[5]) : "v"(p[2][2]), "v"(p[2][3]));
      asm("v_cvt_pk_bf16_f32 %0, %1, %2" : "=v"(wp[6]) : "v"(p[3][0]), "v"(p[3][1]));
      asm("v_cvt_pk_bf16_f32 %0, %1, %2" : "=v"(wp[7]) : "v"(p[3][2]), "v"(p[3][3]));
      u32x4 paw0 = {wp[0], wp[1], wp[2], wp[3]};
      u32x4 paw1 = {wp[4], wp[5], wp[6], wp[7]};
      const bf16x8 pa0 = __builtin_bit_cast(bf16x8, paw0);
      const bf16x8 pa1 = __builtin_bit_cast(bf16x8, paw1);

      // PV: vf = single b128 of pi-permuted V^T tile (cols 32tt+8lg..+7)
#pragma unroll
      for (int tt = 0; tt < 2; tt++)
#pragma unroll
        for (int f8 = 0; f8 < 8; f8++) {
          const bf16x8 vf = *(const bf16x8*)&Vlds[buf][(f8 * 16 + li) * 64 +
                                                       ((tt * 4 + lg) ^ (li & 7)) * 8];
          o[f8] = MFMA16(tt ? pa1 : pa0, vf, o[f8]);
        }
      __builtin_amdgcn_s_barrier();  // all waves done reading buf
      if (it <= 22) STAGE();         // refill buf for iter it+2
    }
#undef STAGE

    float lt = lrow;
    lt += __shfl_xor(lt, 16);
    lt += __shfl_xor(lt, 32);  // half-range denominator for q=li
    const float inv = 1.0f / lt;
    float invi[4];
#pragma unroll
    for (int i = 0; i < 4; i++) invi[i] = __shfl(inv, lg * 4 + i);
#pragma unroll
    for (int i = 0; i < 4; i++) {
      const int row = qrow0 + lg * 4 + i;
#pragma unroll
      for (int f8 = 0; f8 < 8; f8++)
        Opart[(size_t)split * 6553600 + (size_t)row * 2048 + h * 128 + f8 * 16 + li] =
            f2bf(o[f8][i] * invi[i]);
    }
    if (lane < 16) {
      const int row = qrow0 + li;
      ml[(size_t)(split * 16 + h) * 3200 + row] = lt;
    }
  }
}

// ---------------- combine the two KV-split partials (l-weighted, fixed shift) ----------------
__global__ __launch_bounds__(256) void attn_combine(const u16* __restrict__ op,
                                                    const float* __restrict__ ml,
                                                    u16* __restrict__ out) {
  const int row = blockIdx.x, tid = threadIdx.x;
  const int c8 = tid * 8, h = c8 >> 7;
  const float l0 = ml[(size_t)h * 3200 + row];
  const float l1 = ml[(size_t)(16 + h) * 3200 + row];
  const float inv = 1.0f / (l0 + l1);
  const float w0 = l0 * inv, w1 = l1 * inv;
  u16x8 a = *(const u16x8*)&op[(size_t)row * 2048 + c8];
  u16x8 b = *(const u16x8*)&op[6553600 + (size_t)row * 2048 + c8];
  u16x8 r;
#pragma unroll
  for (int j = 0; j < 8; j++)
    r[j] = f2bf(bf2f(a[j]) * w0 + bf2f(b[j]) * w1);
  *(u16x8*)&out[(size_t)row * 2048 + c8] = r;
}

// ---------------- launcher ----------------
extern "C" void kernel_launch(void* const* d_in, const int* in_sizes, int n_in,
                              void* d_out, int out_size, void* d_ws, size_t ws_size,
                              hipStream_t stream) {
  const float* x    = (const float*)d_in[0];
  const float* wq   = (const float*)d_in[1];
  const float* bq   = (const float*)d_in[2];
  const float* wk   = (const float*)d_in[3];
  const float* bk   = (const float*)d_in[4];
  const float* wv   = (const float*)d_in[5];
  const float* bv   = (const float*)d_in[6];
  const float* wo   = (const float*)d_in[7];
  const float* bo   = (const float*)d_in[8];
  const float* nqw  = (const float*)d_in[9];
  const float* nkw  = (const float*)d_in[10];
  const float* fcos = (const float*)d_in[11];
  const float* fsin = (const float*)d_in[12];

  const size_t NEED = 125304832;
  if (ws_size < NEED) return;
  char* ws = (char*)d_ws;
  u16* x_bf   = (u16*)(ws + 0);             // 13.1MB; ml aliases after gemm_qkv
  u16* wq_bf  = (u16*)(ws + 13107200);      // 8.4MB each; counter aliases after gemm_qkv
  u16* wk_bf  = (u16*)(ws + 21495808);
  u16* wv_bf  = (u16*)(ws + 29884416);
  u16* wo_bf  = (u16*)(ws + 38273024);
  u16* preq   = (u16*)(ws + 46661632);      // bf16, dead after rms_rope2
  u16* prek   = (u16*)(ws + 59768832);
  u16* v_bf   = (u16*)(ws + 72876032);      // dead after transpose; att_bf aliases
  u16* q_bf   = (u16*)(ws + 85983232);
  u16* k_bf   = (u16*)(ws + 99090432);
  u16* vT     = (u16*)(ws + 112197632);     // [2048][3200] pi-permuted
  u16* opart  = (u16*)(ws + 46661632);      // 2 x 13.1MB (aliases preq+prek, dead)
  float* ml   = (float*)(ws + 0);           // 2*16*3200 f32 (aliases x_bf, dead)
  int* counter= (int*)(ws + 13107200);      // aliases wq_bf (dead)
  u16* att_bf = (u16*)(ws + 72876032);      // aliases v_bf (dead)

  cast_all<<<11392, 256, 0, stream>>>(x, wq, wk, wv, wo, x_bf, wq_bf, wk_bf, wv_bf,
                                      wo_bf);

  const float foldq = 1.4426950408889634f * 0.08838834764831843f;  // log2e / sqrt(128)

  gemm_qkv<<<dim3(25, 48), 256, 0, stream>>>(x_bf, wq_bf, wk_bf, wv_bf, bq, bk, bv,
                                             preq, prek, v_bf);
  rms_rope2<<<6400, 256, 0, stream>>>(preq, prek, nqw, nkw, fcos, fsin, q_bf, k_bf,
                                      foldq);
  transpose_2d<<<dim3(50, 32), 256, 0, stream>>>(v_bf, vT, counter);
  attn_kernel<<<512, 512, 0, stream>>>(q_bf, k_bf, vT, opart, ml, counter);
  attn_combine<<<3200, 256, 0, stream>>>(opart, ml, att_bf);
  gemm_nt<<<dim3(25, 16), 256, 0, stream>>>(att_bf, wo_bf, bo, (float*)d_out);
}

// Round 18
// 312.582 us; speedup vs baseline: 1.0566x; 1.0566x over previous
//
#include <hip/hip_runtime.h>

typedef unsigned short u16;
typedef unsigned int u32;
typedef __attribute__((ext_vector_type(4))) float f32x4;
typedef __attribute__((ext_vector_type(8))) short bf16x8;   // 8 bf16 bit-patterns (4 VGPRs)
typedef __attribute__((ext_vector_type(8))) u16 u16x8;
typedef __attribute__((ext_vector_type(4))) u16 u16x4;
typedef __attribute__((ext_vector_type(4))) u32 u32x4;

#define GLOB_AS __attribute__((address_space(1)))
#define LDS_AS  __attribute__((address_space(3)))

__device__ __forceinline__ void gload_lds16(const void* g, void* l) {
  // async global->LDS, 16B per lane, LDS dest = wave-uniform base + lane*16
  __builtin_amdgcn_global_load_lds((const GLOB_AS void*)g, (LDS_AS void*)l, 16, 0, 0);
}

__device__ __forceinline__ u16 f2bf(float f) {  // RNE float->bf16
  u32 u = __builtin_bit_cast(u32, f);
  u += 0x7fffu + ((u >> 16) & 1u);
  return (u16)(u >> 16);
}

__device__ __forceinline__ float bf2f(u16 b) {
  u32 u = (u32)b << 16;
  return __builtin_bit_cast(float, u);
}

#define MFMA16(a, b, c) __builtin_amdgcn_mfma_f32_16x16x32_bf16(a, b, c, 0, 0, 0)

// ---------------- fused cast f32 -> bf16 for x + 4 weight matrices ----------------
__global__ __launch_bounds__(256) void cast_all(const float* __restrict__ x,
                                                const float* __restrict__ wq,
                                                const float* __restrict__ wk,
                                                const float* __restrict__ wv,
                                                const float* __restrict__ wo,
                                                u16* __restrict__ xb, u16* __restrict__ wqb,
                                                u16* __restrict__ wkb, u16* __restrict__ wvb,
                                                u16* __restrict__ wob) {
  int i = blockIdx.x * 256 + threadIdx.x;  // 8-element units; boundaries block-uniform
  const float* s;
  u16* d;
  int off;
  if (i < 819200)       { s = x;  d = xb;  off = i; }
  else if (i < 1343488) { s = wq; d = wqb; off = i - 819200; }
  else if (i < 1867776) { s = wk; d = wkb; off = i - 1343488; }
  else if (i < 2392064) { s = wv; d = wvb; off = i - 1867776; }
  else                  { s = wo; d = wob; off = i - 2392064; }
  f32x4 a = ((const f32x4*)s)[2 * off], b = ((const f32x4*)s)[2 * off + 1];
  u16x8 o;
  o[0] = f2bf(a[0]); o[1] = f2bf(a[1]); o[2] = f2bf(a[2]); o[3] = f2bf(a[3]);
  o[4] = f2bf(b[0]); o[5] = f2bf(b[1]); o[6] = f2bf(b[2]); o[7] = f2bf(b[3]);
  ((u16x8*)d)[off] = o;
}

// GEMM K-loop pipeline: dbuf LDS (wide-row XOR layout), prefetch 2 deep, counted
// vmcnt(8), 1 barrier pair per K-step.  (round-14 verified)
#define GEMM_BODY(C_WRITE)                                                        \
  f32x4 acc[4][4] = {};                                                           \
  const u32 dstoff = wave * 2048 + lane * 8; /* u16 units; +512 per chunk */      \
  int gsb = 0;                                                                    \
  const u16* Agp = Ag;                                                            \
  const u16* Bgp = Bg;                                                            \
  _Pragma("unroll") for (int pf = 0; pf < 2; ++pf) {                              \
    u16* ad = &As[gsb][0] + dstoff;                                               \
    u16* bd = &Bs[gsb][0] + dstoff;                                               \
    gload_lds16(Agp, ad);                                                         \
    gload_lds16(Agp + (size_t)8 * K + d4, ad + 512);                              \
    gload_lds16(Agp + (size_t)16 * K, ad + 1024);                                 \
    gload_lds16(Agp + (size_t)24 * K + d4, ad + 1536);                            \
    gload_lds16(Bgp, bd);                                                         \
    gload_lds16(Bgp + (size_t)8 * K + d4, bd + 512);                              \
    gload_lds16(Bgp + (size_t)16 * K, bd + 1024);                                 \
    gload_lds16(Bgp + (size_t)24 * K + d4, bd + 1536);                            \
    Agp += 64;                                                                    \
    Bgp += 64;                                                                    \
    gsb ^= 1;                                                                     \
  }                                                                               \
  for (int it = 0; it < 32; ++it) {                                               \
    const int buf = it & 1;                                                       \
    if (it < 31)                                                                  \
      asm volatile("s_waitcnt vmcnt(8)" ::: "memory");                            \
    else                                                                          \
      asm volatile("s_waitcnt vmcnt(0)" ::: "memory");                            \
    __builtin_amdgcn_s_barrier();                                                 \
    _Pragma("unroll") for (int kk = 0; kk < 64; kk += 32) {                       \
      bf16x8 af[4], bfr[4];                                                       \
      _Pragma("unroll") for (int mi = 0; mi < 4; mi++)                            \
          af[mi] = *(const bf16x8*)&As[buf][((wr + mi * 16 + li) >> 1) * 128 +    \
              ((((kk >> 3) + lg + 8 * (li & 1)) ^ (li >> 1)) * 8)];               \
      _Pragma("unroll") for (int ni = 0; ni < 4; ni++)                            \
          bfr[ni] = *(const bf16x8*)&Bs[buf][((wc + ni * 16 + li) >> 1) * 128 +   \
              ((((kk >> 3) + lg + 8 * (li & 1)) ^ (li >> 1)) * 8)];               \
      _Pragma("unroll") for (int mi = 0; mi < 4; mi++)                            \
          _Pragma("unroll") for (int ni = 0; ni < 4; ni++)                        \
              acc[mi][ni] = MFMA16(af[mi], bfr[ni], acc[mi][ni]);                 \
    }                                                                             \
    __builtin_amdgcn_s_barrier();                                                 \
    if (it <= 29) {                                                               \
      u16* ad = &As[gsb][0] + dstoff;                                             \
      u16* bd = &Bs[gsb][0] + dstoff;                                             \
      gload_lds16(Agp, ad);                                                       \
      gload_lds16(Agp + (size_t)8 * K + d4, ad + 512);                            \
      gload_lds16(Agp + (size_t)16 * K, ad + 1024);                               \
      gload_lds16(Agp + (size_t)24 * K + d4, ad + 1536);                          \
      gload_lds16(Bgp, bd);                                                       \
      gload_lds16(Bgp + (size_t)8 * K + d4, bd + 512);                            \
      gload_lds16(Bgp + (size_t)16 * K, bd + 1024);                               \
      gload_lds16(Bgp + (size_t)24 * K + d4, bd + 1536);                          \
      Agp += 64;                                                                  \
      Bgp += 64;                                                                  \
      gsb ^= 1;                                                                   \
    }                                                                             \
  }                                                                               \
  float bcol[4];                                                                  \
  _Pragma("unroll") for (int ni = 0; ni < 4; ni++)                                \
      bcol[ni] = bias[n0 + wc + ni * 16 + li];                                    \
  _Pragma("unroll") for (int mi = 0; mi < 4; mi++) {                              \
    _Pragma("unroll") for (int ni = 0; ni < 4; ni++) {                            \
      const int gm = m0 + wr + mi * 16 + lg * 4;                                  \
      const int gn = n0 + wc + ni * 16 + li;                                      \
      _Pragma("unroll") for (int r = 0; r < 4; r++) { C_WRITE; }                  \
    }                                                                             \
  }

#define GEMM_STAGE_SETUP()                                        \
  const int Wl = lane >> 4;                                       \
  const int sl = lane & 15;                                       \
  const int gsa = sl ^ Wl;                                        \
  const int d4 = ((((gsa & 7) ^ 4) - (gsa & 7)) * 8)

// ---------------- fused QKV NT GEMM, XCD-chunked; bf16 outputs; pipelined ----------------
__global__ __launch_bounds__(256) void gemm_qkv(const u16* __restrict__ A,
                                                const u16* __restrict__ Bq,
                                                const u16* __restrict__ Bk,
                                                const u16* __restrict__ Bv,
                                                const float* __restrict__ bq,
                                                const float* __restrict__ bk,
                                                const float* __restrict__ bv,
                                                u16* __restrict__ Cq,
                                                u16* __restrict__ Ck,
                                                u16* __restrict__ Cv) {
  constexpr int K = 2048, N = 2048;
  __shared__ u16 As[2][128 * 64];
  __shared__ u16 Bs[2][128 * 64];
  const int tid = threadIdx.x;
  const int wave = tid >> 6, lane = tid & 63;
  const int lg = lane >> 4, li = lane & 15;
  const int lid = blockIdx.x + 25 * blockIdx.y;   // 0..1199, xcd ~ lid&7
  const int tile = (lid & 7) * 150 + (lid >> 3);  // bijective (1200 = 8*150)
  const int bx = tile % 25, by = tile / 25;
  const int m0 = bx * 128;
  const int mat = by >> 4;  // block-uniform
  const int n0 = (by & 15) * 128;
  const u16* B = (mat == 0) ? Bq : (mat == 1) ? Bk : Bv;
  const float* bias = (mat == 0) ? bq : (mat == 1) ? bk : bv;
  u16* C = (mat == 0) ? Cq : (mat == 1) ? Ck : Cv;
  const int wr = (wave >> 1) * 64, wc = (wave & 1) * 64;

  GEMM_STAGE_SETUP();
  const u16* Ag = A + (size_t)(m0 + wave * 32 + 2 * Wl + (sl >> 3)) * K + (gsa & 7) * 8;
  const u16* Bg = B + (size_t)(n0 + wave * 32 + 2 * Wl + (sl >> 3)) * K + (gsa & 7) * 8;

  GEMM_BODY(C[(size_t)(gm + r) * N + gn] = f2bf(acc[mi][ni][r] + bcol[ni]))
}

// ---------------- NT GEMM (out-proj), XCD-chunked, f32 out; pipelined ----------------
__global__ __launch_bounds__(256) void gemm_nt(const u16* __restrict__ A,
                                               const u16* __restrict__ B,
                                               const float* __restrict__ bias,
                                               float* __restrict__ C) {
  constexpr int K = 2048, N = 2048;
  __shared__ u16 As[2][128 * 64];
  __shared__ u16 Bs[2][128 * 64];
  const int tid = threadIdx.x;
  const int wave = tid >> 6, lane = tid & 63;
  const int lg = lane >> 4, li = lane & 15;
  const int lid = blockIdx.x + 25 * blockIdx.y;  // 0..399
  const int tile = (lid & 7) * 50 + (lid >> 3);  // bijective (400 = 8*50)
  const int m0 = (tile % 25) * 128, n0 = (tile / 25) * 128;
  const int wr = (wave >> 1) * 64, wc = (wave & 1) * 64;

  GEMM_STAGE_SETUP();
  const u16* Ag = A + (size_t)(m0 + wave * 32 + 2 * Wl + (sl >> 3)) * K + (gsa & 7) * 8;
  const u16* Bg = B + (size_t)(n0 + wave * 32 + 2 * Wl + (sl >> 3)) * K + (gsa & 7) * 8;

  GEMM_BODY(C[(size_t)(gm + r) * N + gn] = acc[mi][ni][r] + bcol[ni])
}

// ---------------- fused RMSNorm + 3-axis RoPE, bf16 in, q and k in one dispatch ----------------
__global__ __launch_bounds__(256) void rms_rope2(const u16* __restrict__ preq,
                                                 const u16* __restrict__ prek,
                                                 const float* __restrict__ wq,
                                                 const float* __restrict__ wk,
                                                 const float* __restrict__ fcos,
                                                 const float* __restrict__ fsin,
                                                 u16* __restrict__ outq,
                                                 u16* __restrict__ outk, float foldq) {
  const int isk = blockIdx.x >= 3200;  // block-uniform
  const int l = isk ? blockIdx.x - 3200 : blockIdx.x;
  const u16* pre = isk ? prek : preq;
  const float* w = isk ? wk : wq;
  u16* out = isk ? outk : outq;
  const float fold = isk ? 1.0f : foldq;
  const int tid = threadIdx.x;
  const int d0 = tid * 8;
  u16x8 pv = *(const u16x8*)(pre + (size_t)l * 2048 + d0);
  float xv[8];
#pragma unroll
  for (int j = 0; j < 8; j++) xv[j] = bf2f(pv[j]);
  float ss = (xv[0] * xv[0] + xv[1] * xv[1]) + (xv[2] * xv[2] + xv[3] * xv[3]) +
             (xv[4] * xv[4] + xv[5] * xv[5]) + (xv[6] * xv[6] + xv[7] * xv[7]);
#pragma unroll
  for (int m = 32; m; m >>= 1) ss += __shfl_xor(ss, m);
  __shared__ float red[4];
  if ((tid & 63) == 0) red[tid >> 6] = ss;
  __syncthreads();
  const float scale =
      rsqrtf((red[0] + red[1] + red[2] + red[3]) * (1.0f / 2048.0f) + 1e-6f) * fold;
  f32x4 w0 = *(const f32x4*)(w + d0);
  f32x4 w1 = *(const f32x4*)(w + d0 + 4);
  float xs[8];
#pragma unroll
  for (int j = 0; j < 4; j++) {
    xs[j] = xv[j] * w0[j] * scale;
    xs[4 + j] = xv[4 + j] * w1[j] * scale;
  }
  const int f = l / 640, rem = l % 640;
  const int hh = rem >> 5, ww = rem & 31;
  const int cb = (d0 & 127) >> 1;
  u16x8 ov;
#pragma unroll
  for (int i = 0; i < 4; i++) {
    const int c = cb + i;
    const int prow = c < 22 ? f : (c < 43 ? hh : ww);  // S0=22, S0+S1=43
    const float fc = fcos[prow * 64 + c];
    const float fs = fsin[prow * 64 + c];
    const float xr = xs[2 * i], xi = xs[2 * i + 1];
    ov[2 * i] = f2bf(xr * fc - xi * fs);
    ov[2 * i + 1] = f2bf(xr * fs + xi * fc);
  }
  *(u16x8*)(out + (size_t)l * 2048 + d0) = ov;
}

// ---------------- bf16 transpose [3200][2048] -> [2048][3200], pi-permuted ----------------
__global__ __launch_bounds__(256) void transpose_2d(const u16* __restrict__ src,
                                                    u16* __restrict__ dst) {
  __shared__ u16 t[64][72];
  const int m0 = blockIdx.x * 64, n0 = blockIdx.y * 64;
  const int tid = threadIdx.x;
  const int r = tid >> 3, c8 = (tid & 7) * 8;
#pragma unroll
  for (int j = 0; j < 2; j++) {
    u16x8 v = *(const u16x8*)&src[(size_t)(m0 + r + 32 * j) * 2048 + n0 + c8];
#pragma unroll
    for (int e = 0; e < 8; e++) t[c8 + e][r + 32 * j] = v[e];
  }
  __syncthreads();
  const int b = (c8 >> 5) * 32;       // 32-block base within tile
  const int cc = ((c8 >> 3) & 3) * 4; // 4-col group
#pragma unroll
  for (int j = 0; j < 2; j++) {
    const u16* trow = &t[r + 32 * j][0];
    u16x4 lo = *(const u16x4*)&trow[b + cc];
    u16x4 hi = *(const u16x4*)&trow[b + 16 + cc];
    u16x8 v;
    v[0] = lo[0]; v[1] = lo[1]; v[2] = lo[2]; v[3] = lo[3];
    v[4] = hi[0]; v[5] = hi[1]; v[6] = hi[2]; v[7] = hi[3];
    *(u16x8*)&dst[(size_t)(n0 + r + 32 * j) * 3200 + m0 + c8] = v;
  }
}

// ---------------- flash attention v8 (round-16 verified): 8-wave + fixed-shift softmax ----------------
// grid (25,16) XCD-chunked, 400 blocks x 8 waves x 16 q-rows = 128 q/block. KVBLK=64,
// 50 iters. P = exp2(s - 24) fixed shift (RMS-normalized scores bounded << 24).
__global__ __launch_bounds__(512) void attn_kernel(const u16* __restrict__ Q,
                                                   const u16* __restrict__ Kb,
                                                   const u16* __restrict__ VT,
                                                   u16* __restrict__ O) {
  __shared__ u16 Klds[2][64 * 128];
  __shared__ u16 Vlds[2][128 * 64];
  const int tid = threadIdx.x, wave = tid >> 6, lane = tid & 63;
  const int lg = lane >> 4, li = lane & 15;

  const int lid = blockIdx.x + 25 * blockIdx.y;  // 0..399
  const int xcd = lid & 7, ixd = lid >> 3;       // 400 = 8*50 bijective
  const int h = xcd * 2 + (ixd & 1);             // each XCD owns 2 heads (3.2MB < L2)
  const int qrow0 = (ixd >> 1) * 128 + wave * 16;

  bf16x8 qf[4];
  {
    const u16* qb = Q + (size_t)(qrow0 + li) * 2048 + h * 128 + lg * 8;
#pragma unroll
    for (int ks = 0; ks < 4; ks++) qf[ks] = *(const bf16x8*)(qb + ks * 32);
  }
  f32x4 o[8] = {};
  float lrow = 0.f;  // per-lane partial over this lane's 16 kv slots

  // K staging: wave w stages kv rows [8w, 8w+8): gload j in {0,1} -> rows 8w+4j+klp.
  const int klp = lane >> 4;                 // 0..3
  const int kg0 = (lane & 15) ^ klp;         // granule for j=0 (row&7 = klp)
  const int kd4 = ((kg0 ^ 4) - kg0) * 8;     // j=1: granule ^= 4 (row&7 = 4+klp)
  const u16* kp = Kb + (size_t)(wave * 8 + klp) * 2048 + h * 128 + kg0 * 8;
  // V staging: wave w stages d rows [16w, 16w+16): gload j in {0,1} -> rows 16w+8j+vlp.
  const int vlp = lane >> 3;                 // 0..7
  const int vg = (lane & 7) ^ vlp;           // granule (row&7 = vlp, j-independent)
  const u16* vp = VT + (size_t)(h * 128 + wave * 16 + vlp) * 3200 + vg * 8;
  const u32 dstoff = wave * 1024 + lane * 8;  // u16 units; +512 per gload j
  int sb = 0;

#define STAGE()                               \
  do {                                        \
    u16* kd = &Klds[sb][0] + dstoff;          \
    u16* vd = &Vlds[sb][0] + dstoff;          \
    gload_lds16(kp, kd);                      \
    gload_lds16(kp + 4 * 2048 + kd4, kd + 512); \
    gload_lds16(vp, vd);                      \
    gload_lds16(vp + 8 * 3200, vd + 512);     \
    kp += 64 * 2048;                          \
    vp += 64;                                 \
    sb ^= 1;                                  \
  } while (0)

  STAGE();  // iter 0
  STAGE();  // iter 1

  for (int it = 0; it < 50; ++it) {
    const int buf = it & 1;
    if (it < 49)
      asm volatile("s_waitcnt vmcnt(4)" ::: "memory");  // this iter's 4 landed
    else
      asm volatile("s_waitcnt vmcnt(0)" ::: "memory");
    __builtin_amdgcn_s_barrier();

    // QK^T swapped: s4[t][i] = S[kv=16t+4lg+i][q=li]
    f32x4 s4[4] = {};
#pragma unroll
    for (int t = 0; t < 4; t++)
#pragma unroll
      for (int ks = 0; ks < 4; ks++) {
        const bf16x8 kf = *(const bf16x8*)&Klds[buf][(t * 16 + li) * 128 +
                                                     ((ks * 4 + lg) ^ (li & 7)) * 8];
        s4[t] = MFMA16(kf, qf[ks], s4[t]);
      }
    // fixed-shift softmax: P = exp2(s - 24), no max tracking
    f32x4 p[4];
#pragma unroll
    for (int t = 0; t < 4; t++)
#pragma unroll
      for (int i = 0; i < 4; i++) p[t][i] = exp2f(s4[t][i] - 24.0f);
    lrow += ((p[0][0] + p[0][1]) + (p[0][2] + p[0][3])) +
            ((p[1][0] + p[1][1]) + (p[1][2] + p[1][3])) +
            ((p[2][0] + p[2][1]) + (p[2][2] + p[2][3])) +
            ((p[3][0] + p[3][1]) + (p[3][2] + p[3][3]));
    u32 wp[8];
    asm("v_cvt_pk_bf16_f32 %0, %1, %2" : "=v"(wp[0]) : "v"(p[0][0]), "v"(p[0][1]));
    asm("v_cvt_pk_bf16_f32 %0, %1, %2" : "=v"(wp[1]) : "v"(p[0][2]), "v"(p[0][3]));
    asm("v_cvt_pk_bf16_f32 %0, %1, %2" : "=v"(wp[2]) : "v"(p[1][0]), "v"(p[1][1]));
    asm("v_cvt_pk_bf16_f32 %0, %1, %2" : "=v"(wp[3]) : "v"(p[1][2]), "v"(p[1][3]));
    asm("v_cvt_pk_bf16_f32 %0, %1, %2" : "=v"(wp[4]) : "v"(p[2][0]), "v"(p[2][1]));
    asm("v_cvt_pk_bf16_f32 %0, %1, %2" : "=v"(wp[5]) : "v"(p[2][2]), "v"(p[2][3]));
    asm("v_cvt_pk_bf16_f32 %0, %1, %2" : "=v"(wp[6]) : "v"(p[3][0]), "v"(p[3][1]));
    asm("v_cvt_pk_bf16_f32 %0, %1, %2" : "=v"(wp[7]) : "v"(p[3][2]), "v"(p[3][3]));
    u32x4 paw0 = {wp[0], wp[1], wp[2], wp[3]};
    u32x4 paw1 = {wp[4], wp[5], wp[6], wp[7]};
    const bf16x8 pa0 = __builtin_bit_cast(bf16x8, paw0);
    const bf16x8 pa1 = __builtin_bit_cast(bf16x8, paw1);

    // PV: vf = single b128 of pi-permuted V^T tile (cols 32tt+8lg..+7)
#pragma unroll
    for (int tt = 0; tt < 2; tt++)
#pragma unroll
      for (int f8 = 0; f8 < 8; f8++) {
        const bf16x8 vf = *(const bf16x8*)&Vlds[buf][(f8 * 16 + li) * 64 +
                                                     ((tt * 4 + lg) ^ (li & 7)) * 8];
        o[f8] = MFMA16(tt ? pa1 : pa0, vf, o[f8]);
      }
    __builtin_amdgcn_s_barrier();  // all waves done reading buf
    if (it <= 47) STAGE();         // refill buf for iter it+2
  }
#undef STAGE

  float lt = lrow;
  lt += __shfl_xor(lt, 16);
  lt += __shfl_xor(lt, 32);
  const float inv = 1.0f / lt;
  float invi[4];
#pragma unroll
  for (int i = 0; i < 4; i++) invi[i] = __shfl(inv, lg * 4 + i);
#pragma unroll
  for (int i = 0; i < 4; i++) {
    const int row = qrow0 + lg * 4 + i;
#pragma unroll
    for (int f8 = 0; f8 < 8; f8++)
      O[(size_t)row * 2048 + h * 128 + f8 * 16 + li] = f2bf(o[f8][i] * invi[i]);
  }
}

// ---------------- launcher ----------------
extern "C" void kernel_launch(void* const* d_in, const int* in_sizes, int n_in,
                              void* d_out, int out_size, void* d_ws, size_t ws_size,
                              hipStream_t stream) {
  const float* x    = (const float*)d_in[0];
  const float* wq   = (const float*)d_in[1];
  const float* bq   = (const float*)d_in[2];
  const float* wk   = (const float*)d_in[3];
  const float* bk   = (const float*)d_in[4];
  const float* wv   = (const float*)d_in[5];
  const float* bv   = (const float*)d_in[6];
  const float* wo   = (const float*)d_in[7];
  const float* bo   = (const float*)d_in[8];
  const float* nqw  = (const float*)d_in[9];
  const float* nkw  = (const float*)d_in[10];
  const float* fcos = (const float*)d_in[11];
  const float* fsin = (const float*)d_in[12];

  const size_t NEED = 125304832;
  if (ws_size < NEED) return;
  char* ws = (char*)d_ws;
  u16* x_bf   = (u16*)(ws + 0);             // 13.1MB
  u16* wq_bf  = (u16*)(ws + 13107200);      // 8.4MB each
  u16* wk_bf  = (u16*)(ws + 21495808);
  u16* wv_bf  = (u16*)(ws + 29884416);
  u16* wo_bf  = (u16*)(ws + 38273024);
  u16* preq   = (u16*)(ws + 46661632);      // bf16, dead after rms_rope2
  u16* prek   = (u16*)(ws + 59768832);
  u16* v_bf   = (u16*)(ws + 72876032);      // dead after transpose
  u16* q_bf   = (u16*)(ws + 85983232);
  u16* k_bf   = (u16*)(ws + 99090432);
  u16* vT     = (u16*)(ws + 112197632);     // [2048][3200] pi-permuted
  u16* att_bf = (u16*)(ws + 46661632);      // aliases preq (dead)

  cast_all<<<11392, 256, 0, stream>>>(x, wq, wk, wv, wo, x_bf, wq_bf, wk_bf, wv_bf,
                                      wo_bf);

  const float foldq = 1.4426950408889634f * 0.08838834764831843f;  // log2e / sqrt(128)

  gemm_qkv<<<dim3(25, 48), 256, 0, stream>>>(x_bf, wq_bf, wk_bf, wv_bf, bq, bk, bv,
                                             preq, prek, v_bf);
  rms_rope2<<<6400, 256, 0, stream>>>(preq, prek, nqw, nkw, fcos, fsin, q_bf, k_bf,
                                      foldq);
  transpose_2d<<<dim3(50, 32), 256, 0, stream>>>(v_bf, vT);
  attn_kernel<<<dim3(25, 16), 512, 0, stream>>>(q_bf, k_bf, vT, att_bf);
  gemm_nt<<<dim3(25, 16), 256, 0, stream>>>(att_bf, wo_bf, bo, (float*)d_out);
}